// Round 1
// baseline (164.476 us; speedup 1.0000x reference)
//
#include <hip/hip_runtime.h>

// AllGNN: out = ((adj @ (x@W_in + b_in)) / (rowsum(adj)+1)) @ W_cls + b_cls
// N=12000, IN_CH=256, HID=64, N_CLS=40. adj is binary f32, ~0.2% dense.
// Strategy: adj (576 MB) is the only big input -> single fused streaming pass
// computing deg and the sparse aggregation together. One wave per row.

#define NN    12000
#define INCH  256
#define HID   64
#define NCLS  40

// ---------------- Kernel 1: h = x @ W_in + b_in  (one wave per row) --------
__global__ __launch_bounds__(256) void fc_in_kernel(
    const float* __restrict__ x, const float* __restrict__ W_in,
    const float* __restrict__ b_in, float* __restrict__ h)
{
    const int lane = threadIdx.x & 63;
    const int row  = blockIdx.x * 4 + (threadIdx.x >> 6);
    if (row >= NN) return;

    // stage this row of x into registers (4 floats/lane, coalesced)
    const float* xrow = x + (size_t)row * INCH;
    float xr0 = xrow[lane];
    float xr1 = xrow[64 + lane];
    float xr2 = xrow[128 + lane];
    float xr3 = xrow[192 + lane];

    float acc = b_in[lane];   // lane owns hidden channel `lane`
    #pragma unroll 8
    for (int c = 0; c < 64; ++c) {
        float x0 = __shfl(xr0, c);
        float x1 = __shfl(xr1, c);
        float x2 = __shfl(xr2, c);
        float x3 = __shfl(xr3, c);
        acc = fmaf(x0, W_in[(c)       * HID + lane], acc);
        acc = fmaf(x1, W_in[(c + 64)  * HID + lane], acc);
        acc = fmaf(x2, W_in[(c + 128) * HID + lane], acc);
        acc = fmaf(x3, W_in[(c + 192) * HID + lane], acc);
    }
    h[(size_t)row * HID + lane] = acc;
}

// ------- Kernel 2: fused deg + sparse aggregation + classifier head --------
// One wave per adjacency row. Lane owns hidden channel `lane` of agg.
__global__ __launch_bounds__(256) void gnn_agg_kernel(
    const float* __restrict__ adj, const float* __restrict__ h,
    const float* __restrict__ W_cls, const float* __restrict__ b_cls,
    float* __restrict__ out)
{
    const int lane = threadIdx.x & 63;
    const int row  = blockIdx.x * 4 + (threadIdx.x >> 6);
    if (row >= NN) return;

    const float* __restrict__ arow = adj + (size_t)row * NN;

    float acc    = 0.0f;   // agg[row][lane]
    float degloc = 0.0f;

    // scan 12000 cols in chunks of 256 (lane l covers cols chunk+4l..chunk+4l+3)
    for (int chunk = 0; chunk < NN; chunk += 256) {
        const int base = chunk + lane * 4;
        float4 v = make_float4(0.f, 0.f, 0.f, 0.f);
        if (base < NN) v = *reinterpret_cast<const float4*>(arow + base);
        degloc += (v.x + v.y) + (v.z + v.w);

        unsigned long long m;
        m = __ballot(v.x != 0.0f);
        while (m) {
            int l = (int)__builtin_ctzll(m); m &= m - 1;
            float a = __shfl(v.x, l);
            acc = fmaf(a, h[(size_t)(chunk + l * 4 + 0) * HID + lane], acc);
        }
        m = __ballot(v.y != 0.0f);
        while (m) {
            int l = (int)__builtin_ctzll(m); m &= m - 1;
            float a = __shfl(v.y, l);
            acc = fmaf(a, h[(size_t)(chunk + l * 4 + 1) * HID + lane], acc);
        }
        m = __ballot(v.z != 0.0f);
        while (m) {
            int l = (int)__builtin_ctzll(m); m &= m - 1;
            float a = __shfl(v.z, l);
            acc = fmaf(a, h[(size_t)(chunk + l * 4 + 2) * HID + lane], acc);
        }
        m = __ballot(v.w != 0.0f);
        while (m) {
            int l = (int)__builtin_ctzll(m); m &= m - 1;
            float a = __shfl(v.w, l);
            acc = fmaf(a, h[(size_t)(chunk + l * 4 + 3) * HID + lane], acc);
        }
    }

    // wave-reduce degree (all lanes end with the total)
    float deg = degloc;
    #pragma unroll
    for (int off = 32; off; off >>= 1) deg += __shfl_xor(deg, off);

    const float agg = acc * __frcp_rn(deg + 1.0f) ;

    // head: out[row][c] = sum_k agg[k] * W_cls[k][c] + b_cls[c]
    const int cl = (lane < NCLS) ? lane : 0;   // clamp to stay in-bounds, no divergence
    float o = b_cls[cl];
    #pragma unroll 8
    for (int k = 0; k < HID; ++k) {
        float a = __shfl(agg, k);
        o = fmaf(a, W_cls[k * NCLS + cl], o);
    }
    if (lane < NCLS) out[(size_t)row * NCLS + lane] = o;
}

extern "C" void kernel_launch(void* const* d_in, const int* in_sizes, int n_in,
                              void* d_out, int out_size, void* d_ws, size_t ws_size,
                              hipStream_t stream)
{
    const float* x     = (const float*)d_in[0];
    const float* adj   = (const float*)d_in[1];
    const float* W_in  = (const float*)d_in[2];
    const float* b_in  = (const float*)d_in[3];
    const float* W_cls = (const float*)d_in[4];
    const float* b_cls = (const float*)d_in[5];
    float* out = (float*)d_out;
    float* h   = (float*)d_ws;               // 12000*64*4 = 3 MB scratch

    const int blocks = (NN + 3) / 4;         // 4 waves/block, 1 row/wave
    fc_in_kernel<<<blocks, 256, 0, stream>>>(x, W_in, b_in, h);
    gnn_agg_kernel<<<blocks, 256, 0, stream>>>(adj, h, W_cls, b_cls, out);
}

// Round 2
// 149.779 us; speedup vs baseline: 1.0981x; 1.0981x over previous
//
#include <hip/hip_runtime.h>

// AllGNN: out = ((adj @ (x@W_in + b_in)) / (rowsum(adj)+1)) @ W_cls + b_cls
// N=12000, IN_CH=256, HID=64, N_CLS=40. adj is binary f32, ~0.2% dense.
// adj (576 MB) dominates -> single fused streaming pass (deg + aggregation),
// one wave per row, 4 chunks (4 KB) in flight per wave for MLP.

#define NN    12000
#define INCH  256
#define HID   64
#define NCLS  40

typedef float f4 __attribute__((ext_vector_type(4)));

// ---------------- Kernel 1: h = x @ W_in + b_in  (one wave per row) --------
__global__ __launch_bounds__(256) void fc_in_kernel(
    const float* __restrict__ x, const float* __restrict__ W_in,
    const float* __restrict__ b_in, float* __restrict__ h)
{
    const int lane = threadIdx.x & 63;
    const int row  = blockIdx.x * 4 + (threadIdx.x >> 6);
    if (row >= NN) return;

    const float* xrow = x + (size_t)row * INCH;
    float xr0 = xrow[lane];
    float xr1 = xrow[64 + lane];
    float xr2 = xrow[128 + lane];
    float xr3 = xrow[192 + lane];

    float acc = b_in[lane];   // lane owns hidden channel `lane`
    #pragma unroll 8
    for (int c = 0; c < 64; ++c) {
        float x0 = __shfl(xr0, c);
        float x1 = __shfl(xr1, c);
        float x2 = __shfl(xr2, c);
        float x3 = __shfl(xr3, c);
        acc = fmaf(x0, W_in[(c)       * HID + lane], acc);
        acc = fmaf(x1, W_in[(c + 64)  * HID + lane], acc);
        acc = fmaf(x2, W_in[(c + 128) * HID + lane], acc);
        acc = fmaf(x3, W_in[(c + 192) * HID + lane], acc);
    }
    h[(size_t)row * HID + lane] = acc;
}

// ------- Kernel 2: fused deg + sparse aggregation + classifier head --------
// One wave per adjacency row; lane owns hidden channel `lane` of agg.
__global__ __launch_bounds__(256) void gnn_agg_kernel(
    const float* __restrict__ adj, const float* __restrict__ h,
    const float* __restrict__ W_cls, const float* __restrict__ b_cls,
    float* __restrict__ out)
{
    const int lane = threadIdx.x & 63;
    const int row  = blockIdx.x * 4 + (threadIdx.x >> 6);
    if (row >= NN) return;

    const float* __restrict__ arow = adj + (size_t)row * NN;
    const int bl = lane * 4;

    float acc = 0.0f;   // agg[row][lane]
    float deg = 0.0f;

    // process one 256-col chunk held in a float4
    auto process = [&](f4 v, int colbase) {
        float s = (v[0] + v[1]) + (v[2] + v[3]);   // adj >= 0, so s!=0 <=> any nz
        deg += s;
        unsigned long long m = __ballot(s != 0.0f);
        while (m) {
            int l = (int)__builtin_ctzll(m); m &= m - 1;
            int col = colbase + l * 4;
            float a0 = __shfl(v[0], l);
            float a1 = __shfl(v[1], l);
            float a2 = __shfl(v[2], l);
            float a3 = __shfl(v[3], l);
            const float* hc = h + (size_t)col * HID + lane;
            if (a0 != 0.0f) acc = fmaf(a0, hc[0 * HID], acc);
            if (a1 != 0.0f) acc = fmaf(a1, hc[1 * HID], acc);
            if (a2 != 0.0f) acc = fmaf(a2, hc[2 * HID], acc);
            if (a3 != 0.0f) acc = fmaf(a3, hc[3 * HID], acc);
        }
    };

    int chunk = 0;
    // main loop: 4 chunks (1024 cols) per iteration, 4 loads in flight
    for (; chunk + 1024 <= NN; chunk += 1024) {
        const float* p = arow + chunk + bl;
        f4 v0 = __builtin_nontemporal_load(reinterpret_cast<const f4*>(p));
        f4 v1 = __builtin_nontemporal_load(reinterpret_cast<const f4*>(p + 256));
        f4 v2 = __builtin_nontemporal_load(reinterpret_cast<const f4*>(p + 512));
        f4 v3 = __builtin_nontemporal_load(reinterpret_cast<const f4*>(p + 768));
        process(v0, chunk);
        process(v1, chunk + 256);
        process(v2, chunk + 512);
        process(v3, chunk + 768);
    }
    // tail: masked single chunks (NN % 4 == 0, so base<NN => full float4 ok)
    for (; chunk < NN; chunk += 256) {
        const int base = chunk + bl;
        f4 v = {0.f, 0.f, 0.f, 0.f};
        if (base < NN)
            v = __builtin_nontemporal_load(reinterpret_cast<const f4*>(arow + base));
        process(v, chunk);
    }

    // wave-reduce degree (all lanes end with the total)
    #pragma unroll
    for (int off = 32; off; off >>= 1) deg += __shfl_xor(deg, off);

    const float agg = acc * __frcp_rn(deg + 1.0f);

    // head: out[row][c] = sum_k agg[k] * W_cls[k][c] + b_cls[c]
    const int cl = (lane < NCLS) ? lane : 0;   // clamp, no divergence
    float o = b_cls[cl];
    #pragma unroll 8
    for (int k = 0; k < HID; ++k) {
        float a = __shfl(agg, k);
        o = fmaf(a, W_cls[k * NCLS + cl], o);
    }
    if (lane < NCLS) out[(size_t)row * NCLS + lane] = o;
}

extern "C" void kernel_launch(void* const* d_in, const int* in_sizes, int n_in,
                              void* d_out, int out_size, void* d_ws, size_t ws_size,
                              hipStream_t stream)
{
    const float* x     = (const float*)d_in[0];
    const float* adj   = (const float*)d_in[1];
    const float* W_in  = (const float*)d_in[2];
    const float* b_in  = (const float*)d_in[3];
    const float* W_cls = (const float*)d_in[4];
    const float* b_cls = (const float*)d_in[5];
    float* out = (float*)d_out;
    float* h   = (float*)d_ws;               // 12000*64*4 = 3 MB scratch

    const int blocks = (NN + 3) / 4;         // 4 waves/block, 1 row/wave
    fc_in_kernel<<<blocks, 256, 0, stream>>>(x, W_in, b_in, h);
    gnn_agg_kernel<<<blocks, 256, 0, stream>>>(adj, h, W_cls, b_cls, out);
}

// Round 3
// 143.333 us; speedup vs baseline: 1.1475x; 1.0450x over previous
//
#include <hip/hip_runtime.h>

// AllGNN: out = ((adj @ (x@W_in + b_in)) / (rowsum(adj)+1)) @ W_cls + b_cls
// N=12000, IN_CH=256, HID=64, N_CLS=40. adj is binary f32, ~0.2% dense.
// adj (576 MB) dominates -> one BLOCK per row, 4 waves each scanning every
// 4th 256-col chunk with a 2-pair prefetch pipeline; LDS combine + head.

#define NN     12000
#define INCH   256
#define HID    64
#define NCLS   40
#define NCHUNK ((NN + 255) / 256)   // 47

typedef float f4 __attribute__((ext_vector_type(4)));

// ---------------- Kernel 1: h = x @ W_in + b_in  (one wave per row) --------
__global__ __launch_bounds__(256) void fc_in_kernel(
    const float* __restrict__ x, const float* __restrict__ W_in,
    const float* __restrict__ b_in, float* __restrict__ h)
{
    const int lane = threadIdx.x & 63;
    const int row  = blockIdx.x * 4 + (threadIdx.x >> 6);
    if (row >= NN) return;

    const float* xrow = x + (size_t)row * INCH;
    float xr0 = xrow[lane];
    float xr1 = xrow[64 + lane];
    float xr2 = xrow[128 + lane];
    float xr3 = xrow[192 + lane];

    float acc = b_in[lane];   // lane owns hidden channel `lane`
    #pragma unroll 8
    for (int c = 0; c < 64; ++c) {
        float x0 = __shfl(xr0, c);
        float x1 = __shfl(xr1, c);
        float x2 = __shfl(xr2, c);
        float x3 = __shfl(xr3, c);
        acc = fmaf(x0, W_in[(c)       * HID + lane], acc);
        acc = fmaf(x1, W_in[(c + 64)  * HID + lane], acc);
        acc = fmaf(x2, W_in[(c + 128) * HID + lane], acc);
        acc = fmaf(x3, W_in[(c + 192) * HID + lane], acc);
    }
    h[(size_t)row * HID + lane] = acc;
}

// ------- Kernel 2: fused deg + sparse aggregation + classifier head --------
// One BLOCK per adjacency row; 4 waves stride chunks; lane owns hid channel.
__global__ __launch_bounds__(256) void gnn_agg_kernel(
    const float* __restrict__ adj, const float* __restrict__ h,
    const float* __restrict__ W_cls, const float* __restrict__ b_cls,
    float* __restrict__ out)
{
    const int lane = threadIdx.x & 63;
    const int w    = threadIdx.x >> 6;          // wave id 0..3
    const int row  = blockIdx.x;

    __shared__ float s_acc[4][HID];
    __shared__ float s_deg[4];

    const float* __restrict__ arow = adj + (size_t)row * NN;
    const int bl = lane * 4;

    float acc = 0.0f;   // partial agg[row][lane] for this wave
    float deg = 0.0f;

    auto loadc = [&](int ci) -> f4 {
        const int base = ci * 256 + bl;
        f4 v = {0.f, 0.f, 0.f, 0.f};
        if (base + 4 <= NN)   // NN % 4 == 0: either fully in or fully out
            v = __builtin_nontemporal_load(reinterpret_cast<const f4*>(arow + base));
        return v;
    };

    auto process = [&](f4 v, int colbase) {
        float s = (v[0] + v[1]) + (v[2] + v[3]);  // adj >= 0: s!=0 <=> any nz
        deg += s;
        unsigned long long m = __ballot(s != 0.0f);
        while (m) {
            int l = (int)__builtin_ctzll(m); m &= m - 1;
            int col = colbase + l * 4;
            float a0 = __shfl(v[0], l);
            float a1 = __shfl(v[1], l);
            float a2 = __shfl(v[2], l);
            float a3 = __shfl(v[3], l);
            const float* hc = h + (size_t)col * HID + lane;
            if (a0 != 0.0f) acc = fmaf(a0, hc[0 * HID], acc);
            if (a1 != 0.0f) acc = fmaf(a1, hc[1 * HID], acc);
            if (a2 != 0.0f) acc = fmaf(a2, hc[2 * HID], acc);
            if (a3 != 0.0f) acc = fmaf(a3, hc[3 * HID], acc);
        }
    };

    // wave w owns chunks w, w+4, w+8, ... ; pipeline: prefetch next pair
    f4 v0 = loadc(w);                               // w < 47 always
    f4 v1 = (w + 4 < NCHUNK) ? loadc(w + 4) : f4{0.f, 0.f, 0.f, 0.f};
    for (int c = w; c < NCHUNK; c += 8) {
        f4 p0 = {0.f, 0.f, 0.f, 0.f}, p1 = {0.f, 0.f, 0.f, 0.f};
        if (c + 8  < NCHUNK) p0 = loadc(c + 8);
        if (c + 12 < NCHUNK) p1 = loadc(c + 12);
        process(v0, c * 256);
        process(v1, (c + 4) * 256);   // zero vector if OOB: ballot=0, no-op
        v0 = p0; v1 = p1;
    }

    // wave-reduce deg, publish partials
    #pragma unroll
    for (int off = 32; off; off >>= 1) deg += __shfl_xor(deg, off);
    s_acc[w][lane] = acc;
    if (lane == 0) s_deg[w] = deg;
    __syncthreads();

    if (w == 0) {
        float a  = (s_acc[0][lane] + s_acc[1][lane])
                 + (s_acc[2][lane] + s_acc[3][lane]);
        float dt = (s_deg[0] + s_deg[1]) + (s_deg[2] + s_deg[3]);
        float agg = a * __frcp_rn(dt + 1.0f);

        const int cl = (lane < NCLS) ? lane : 0;   // clamp, no divergence
        float o = b_cls[cl];
        #pragma unroll 8
        for (int k = 0; k < HID; ++k) {
            float av = __shfl(agg, k);
            o = fmaf(av, W_cls[k * NCLS + cl], o);
        }
        if (lane < NCLS) out[(size_t)row * NCLS + lane] = o;
    }
}

extern "C" void kernel_launch(void* const* d_in, const int* in_sizes, int n_in,
                              void* d_out, int out_size, void* d_ws, size_t ws_size,
                              hipStream_t stream)
{
    const float* x     = (const float*)d_in[0];
    const float* adj   = (const float*)d_in[1];
    const float* W_in  = (const float*)d_in[2];
    const float* b_in  = (const float*)d_in[3];
    const float* W_cls = (const float*)d_in[4];
    const float* b_cls = (const float*)d_in[5];
    float* out = (float*)d_out;
    float* h   = (float*)d_ws;               // 12000*64*4 = 3 MB scratch

    fc_in_kernel<<<(NN + 3) / 4, 256, 0, stream>>>(x, W_in, b_in, h);
    gnn_agg_kernel<<<NN, 256, 0, stream>>>(adj, h, W_cls, b_cls, out);
}

// Round 4
// 114.916 us; speedup vs baseline: 1.4313x; 1.2473x over previous
//
#include <hip/hip_runtime.h>

// AllGNN: out = ((adj @ (x@W_in + b_in)) / (rowsum(adj)+1)) @ W_cls + b_cls
// N=12000, IN_CH=256, HID=64, N_CLS=40. adj binary f32, ~0.2% dense (576 MB).
// Two-phase aggregation: Phase A streams adj with NO vmcnt-entangled gathers
// (nz pushed to per-wave LDS lists); Phase B drains lists with pipelined L2
// gathers. fc_in: 4 rows/wave for 4x W_in reuse, scalar x broadcasts.

#define NN     12000
#define INCH   256
#define HID    64
#define NCLS   40
#define NCHUNK ((NN + 255) / 256)   // 47
#define CAP    512                   // per-wave nz list capacity (E[nz]~6)

typedef float f4 __attribute__((ext_vector_type(4)));

// ---------------- Kernel 1: h = x @ W_in + b_in  (4 rows per wave) ---------
__global__ __launch_bounds__(256) void fc_in_kernel(
    const float* __restrict__ x, const float* __restrict__ W_in,
    const float* __restrict__ b_in, float* __restrict__ h)
{
    const int lane = threadIdx.x & 63;
    const int w    = threadIdx.x >> 6;
    int rbase = (blockIdx.x * 4 + w) * 4;            // 750 blocks * 16 rows
    rbase = __builtin_amdgcn_readfirstlane(rbase);   // force SGPR base -> s_load x

    const float* __restrict__ xr = x + (size_t)rbase * INCH;
    const float  b = b_in[lane];                     // lane owns hid channel
    float acc0 = b, acc1 = b, acc2 = b, acc3 = b;

    #pragma unroll 8
    for (int c = 0; c < INCH; ++c) {
        float wv = W_in[c * HID + lane];             // 256B/wave, reused x4 rows
        acc0 = fmaf(xr[c],            wv, acc0);     // uniform addr -> scalar ld
        acc1 = fmaf(xr[INCH + c],     wv, acc1);
        acc2 = fmaf(xr[2 * INCH + c], wv, acc2);
        acc3 = fmaf(xr[3 * INCH + c], wv, acc3);
    }
    float* hp = h + (size_t)rbase * HID + lane;
    hp[0 * HID] = acc0;
    hp[1 * HID] = acc1;
    hp[2 * HID] = acc2;
    hp[3 * HID] = acc3;
}

// ------- Kernel 2: fused deg + sparse aggregation + classifier head --------
// One BLOCK per adjacency row; 4 waves stride chunks; lane owns hid channel.
__global__ __launch_bounds__(256) void gnn_agg_kernel(
    const float* __restrict__ adj, const float* __restrict__ h,
    const float* __restrict__ W_cls, const float* __restrict__ b_cls,
    float* __restrict__ out)
{
    const int lane = threadIdx.x & 63;
    const int w    = threadIdx.x >> 6;          // wave id 0..3
    const int row  = blockIdx.x;

    __shared__ int   s_cnt[4];
    __shared__ int   s_col[4][CAP];
    __shared__ float s_val[4][CAP];
    __shared__ float s_acc[4][HID];
    __shared__ float s_deg[4];

    if (lane == 0) s_cnt[w] = 0;                // per-wave, same-wave DS order ok

    const float* __restrict__ arow = adj + (size_t)row * NN;
    const int bl = lane * 4;
    float deg = 0.0f;

    auto loadc = [&](int ci) -> f4 {
        const int base = ci * 256 + bl;
        f4 v = {0.f, 0.f, 0.f, 0.f};
        if (base + 4 <= NN)                      // per-lane OOB guard
            v = __builtin_nontemporal_load(reinterpret_cast<const f4*>(arow + base));
        return v;
    };
    // Phase A scan: NO global gathers here -> adj stream never waits on them
    auto scan = [&](f4 v, int ci) {
        deg += (v[0] + v[1]) + (v[2] + v[3]);
        const int col = ci * 256 + bl;
        #pragma unroll
        for (int i = 0; i < 4; ++i) {
            if (v[i] != 0.0f) {                  // rare: ~0.5 lanes per chunk
                int idx = atomicAdd(&s_cnt[w], 1);   // ds_add_rtn (lgkmcnt)
                if (idx < CAP) { s_col[w][idx] = col + i; s_val[w][idx] = v[i]; }
            }
        }
    };

    // wave w owns chunks w, w+4, ...; groups of 4 -> 4 KB in flight per wave
    for (int c = w; c < NCHUNK; c += 16) {
        f4 v0 = loadc(c);
        f4 v1 = (c + 4  < NCHUNK) ? loadc(c + 4)  : f4{0.f, 0.f, 0.f, 0.f};
        f4 v2 = (c + 8  < NCHUNK) ? loadc(c + 8)  : f4{0.f, 0.f, 0.f, 0.f};
        f4 v3 = (c + 12 < NCHUNK) ? loadc(c + 12) : f4{0.f, 0.f, 0.f, 0.f};
        scan(v0, c);
        scan(v1, c + 4);
        scan(v2, c + 8);
        scan(v3, c + 12);
    }

    // Phase B: drain this wave's nz list with 4 independent gathers in flight
    float acc = 0.0f;
    int n = s_cnt[w];                            // same-wave DS ordering
    n = (n < CAP) ? n : CAP;
    int i = 0;
    for (; i + 4 <= n; i += 4) {
        int   c0 = s_col[w][i],     c1 = s_col[w][i + 1];
        int   c2 = s_col[w][i + 2], c3 = s_col[w][i + 3];
        float a0 = s_val[w][i],     a1 = s_val[w][i + 1];
        float a2 = s_val[w][i + 2], a3 = s_val[w][i + 3];
        float h0 = h[(size_t)c0 * HID + lane];
        float h1 = h[(size_t)c1 * HID + lane];
        float h2 = h[(size_t)c2 * HID + lane];
        float h3 = h[(size_t)c3 * HID + lane];
        acc = fmaf(a0, h0, fmaf(a1, h1, fmaf(a2, h2, fmaf(a3, h3, acc))));
    }
    for (; i < n; ++i)
        acc = fmaf(s_val[w][i], h[(size_t)s_col[w][i] * HID + lane], acc);

    // wave-reduce deg, publish partials
    #pragma unroll
    for (int off = 32; off; off >>= 1) deg += __shfl_xor(deg, off);
    s_acc[w][lane] = acc;
    if (lane == 0) s_deg[w] = deg;
    __syncthreads();

    if (w == 0) {
        float a  = (s_acc[0][lane] + s_acc[1][lane])
                 + (s_acc[2][lane] + s_acc[3][lane]);
        float dt = (s_deg[0] + s_deg[1]) + (s_deg[2] + s_deg[3]);
        float agg = a * __frcp_rn(dt + 1.0f);

        const int cl = (lane < NCLS) ? lane : 0;   // clamp, no divergence
        float o = b_cls[cl];
        #pragma unroll 8
        for (int k = 0; k < HID; ++k) {
            float av = __shfl(agg, k);
            o = fmaf(av, W_cls[k * NCLS + cl], o);
        }
        if (lane < NCLS) out[(size_t)row * NCLS + lane] = o;
    }
}

extern "C" void kernel_launch(void* const* d_in, const int* in_sizes, int n_in,
                              void* d_out, int out_size, void* d_ws, size_t ws_size,
                              hipStream_t stream)
{
    const float* x     = (const float*)d_in[0];
    const float* adj   = (const float*)d_in[1];
    const float* W_in  = (const float*)d_in[2];
    const float* b_in  = (const float*)d_in[3];
    const float* W_cls = (const float*)d_in[4];
    const float* b_cls = (const float*)d_in[5];
    float* out = (float*)d_out;
    float* h   = (float*)d_ws;               // 12000*64*4 = 3 MB scratch

    fc_in_kernel<<<NN / 16, 256, 0, stream>>>(x, W_in, b_in, h);
    gnn_agg_kernel<<<NN, 256, 0, stream>>>(adj, h, W_cls, b_cls, out);
}